// Round 6
// baseline (508.749 us; speedup 1.0000x reference)
//
#include <hip/hip_runtime.h>
#include <stdint.h>

#define THRESH 0.5f
#define DECAY  0.2f
#define TSTEPS 5

#define B_        32
#define CONV_ELEMS (32*256*20*20)   // 3,276,800  (NHWC: [b][y][x][ic])
#define RR        1152
#define CC        10
#define PRIM_ELEMS (32*1152*8)      // 294,912
#define DIG_ELEMS  (32*1152*160)    // 5,898,240
#define MM        256
#define NN        1152
#define KK        20736             // 81 windows * 256 ic, k' = kw*256+ic
#define KSPLIT    24
#define NCH32     27                // 32-elem K chunks per ks slice (27*32 = 864)

typedef __attribute__((ext_vector_type(8))) short bf16x8;
typedef __attribute__((ext_vector_type(4))) float f32x4;
typedef __attribute__((ext_vector_type(4))) unsigned short u16x4;

__device__ __forceinline__ unsigned short f32_to_bf16(float f) {
    uint32_t u = __float_as_uint(f);
    uint32_t r = 0x7FFFu + ((u >> 16) & 1u);
    return (unsigned short)((u + r) >> 16);
}
__device__ __forceinline__ float bf16_to_f32(unsigned short h) {
    return __uint_as_float(((uint32_t)h) << 16);
}

__device__ __forceinline__ void async16(void* l, const void* g) {
    __builtin_amdgcn_global_load_lds(
        (const __attribute__((address_space(1))) uint32_t*)g,
        (__attribute__((address_space(3))) uint32_t*)l, 16, 0, 0);
}

// ---------------- init ----------------
__global__ void k_init_bij(float* bij) {
    int i = blockIdx.x * 256 + threadIdx.x;
    if (i < RR * CC) bij[i] = 1.0f / 1152.0f;
}

// ---------------- conv1 (once): compute NCHW-style, emit NHWC via LDS transpose ----------------
__global__ __launch_bounds__(320) void k_conv1(const float* __restrict__ data,
                                               const float* __restrict__ cw,
                                               const float* __restrict__ cb,
                                               float* __restrict__ out) {
    __shared__ float sdat[784];
    __shared__ float swt[1296];
    __shared__ float sout[20 * 333];
    int b = blockIdx.x, og = blockIdx.y;
    int tid = threadIdx.x;
    for (int i = tid; i < 196; i += 320)
        ((f32x4*)sdat)[i] = ((const f32x4*)(data + b * 784))[i];
    for (int i = tid; i < 324; i += 320)
        ((f32x4*)swt)[i] = ((const f32x4*)(cw + og * 1296))[i];
    __syncthreads();
    int ocl = tid / 20, y = tid % 20;
    float acc[20];
    #pragma unroll
    for (int x = 0; x < 20; ++x) acc[x] = 0.f;
    const float* wb = &swt[ocl * 81];
    #pragma unroll
    for (int ky = 0; ky < 9; ++ky) {
        const float* dr = &sdat[(y + ky) * 28];
        float d[28];
        #pragma unroll
        for (int t4 = 0; t4 < 7; ++t4) {
            f32x4 v = ((const f32x4*)dr)[t4];
            d[t4 * 4 + 0] = v.x; d[t4 * 4 + 1] = v.y;
            d[t4 * 4 + 2] = v.z; d[t4 * 4 + 3] = v.w;
        }
        float w[9];
        #pragma unroll
        for (int q = 0; q < 9; ++q) w[q] = wb[ky * 9 + q];
        #pragma unroll
        for (int kx = 0; kx < 9; ++kx)
            #pragma unroll
            for (int x = 0; x < 20; ++x)
                acc[x] += d[x + kx] * w[kx];
    }
    float bias = cb[og * 16 + ocl];
    #pragma unroll
    for (int x = 0; x < 20; ++x)
        sout[y * 333 + x * 16 + ocl] = fmaxf(acc[x] + bias, 0.f);
    __syncthreads();
    const size_t base = (size_t)b * 102400 + og * 16;
    for (int f = tid; f < 6400; f += 320) {
        int yy = f / 320, rem = f % 320;
        out[base + (size_t)(f >> 4) * 256 + (f & 15)] = sout[yy * 333 + rem];
    }
}

// ---------------- weight split+relayout (once): A'[oc][kw*256+ic] bf16 hi/lo ----------------
__global__ __launch_bounds__(256) void k_wsplit(const float* __restrict__ w,
                                                unsigned short* __restrict__ hi,
                                                unsigned short* __restrict__ lo) {
    int oc = blockIdx.x, ic = threadIdx.x;
    const float* src = w + (size_t)oc * 20736 + ic * 81;
    unsigned short* dh = hi + (size_t)oc * 20736 + ic;
    unsigned short* dl = lo + (size_t)oc * 20736 + ic;
    for (int kw = 0; kw < 81; ++kw) {
        float f = src[kw];
        unsigned short h = f32_to_bf16(f);
        dh[kw * 256] = h;
        dl[kw * 256] = f32_to_bf16(f - bf16_to_f32(h));
    }
}

// ---------------- conv membrane update body ----------------
__device__ __forceinline__ void convmem_body(int i, float* mem, const float* cout,
                                             unsigned short* spk) {
    f32x4 m = ((f32x4*)mem)[i];
    f32x4 c = ((const f32x4*)cout)[i];
    u16x4 sp;
    #pragma unroll
    for (int j = 0; j < 4; ++j) {
        float mv = m[j];
        float ps = (mv > THRESH) ? THRESH : 0.f;
        mv = (mv - ps) * DECAY + c[j];
        m[j] = mv;
        sp[j] = (mv > THRESH) ? (unsigned short)0x3F80 : (unsigned short)0;
    }
    ((f32x4*)mem)[i] = m;
    ((u16x4*)spk)[i] = sp;
}

__global__ void k_convmem(float* __restrict__ mem, const float* __restrict__ cout,
                          unsigned short* __restrict__ spk) {
    int i = blockIdx.x * 256 + threadIdx.x;
    if (i >= CONV_ELEMS / 4) return;
    convmem_body(i, mem, cout, spk);
}

// ---------------- fused-B split-K MFMA GEMM, 64x128 tile, BK=32, paired-row LDS ----------------
// LDS rows are 128 B (bank-0 aligned); 8 x 16 B slots, proven XOR swizzle slot^=(row&7).
// sA row r: slots 0-3 = A-hi[r], slots 4-7 = A-lo[r].  sB row r: slots 0-3 = n-row r,
// slots 4-7 = n-row r+64.
__global__ __launch_bounds__(256) void k_gemm(const unsigned short* __restrict__ Ahi,
                                              const unsigned short* __restrict__ Alo,
                                              const unsigned short* __restrict__ spk,
                                              float* __restrict__ Cp) {
    __shared__ unsigned short sA[2][64 * 64];
    __shared__ unsigned short sB[2][64 * 64];
    int bid = blockIdx.x;
    int slot = bid & 7, j = bid >> 3;          // 864 = 8 * 108
    int tm = slot & 3, kpar = slot >> 2;       // blocks sharing (tm,ks) share bid%8 -> same XCD
    int tn = j / 12, ks2 = j % 12;
    int ks = ks2 * 2 + kpar;                   // 0..23
    int tid = threadIdx.x;

    // staging geometry: LDS row r0 = tid>>3 (pass0) / +32 (pass1); phys slot p = tid&7
    int r0 = tid >> 3;
    int p8 = tid & 7;
    int s = p8 ^ (r0 & 7);                     // logical slot (same for both passes)
    int scol = (s & 3) * 8;                    // k-col offset within 32-elem chunk
    // A source (hi for s<4, lo for s>=4)
    size_t arow = (size_t)(tm * 64 + r0) * KK + (size_t)ks * 864 + scol;
    const unsigned short* pA0 = (s < 4 ? Ahi : Alo) + arow;
    const unsigned short* pA1 = pA0 + (size_t)32 * KK;
    // B source rows
    int nr0 = tn * 128 + ((s < 4) ? r0 : r0 + 64);
    int nr1 = tn * 128 + ((s < 4) ? r0 + 32 : r0 + 96);
    int b0 = nr0 / 36, q0 = nr0 % 36, b1 = nr1 / 36, q1 = nr1 % 36;
    int rb0 = ((b0 * 20 + (q0 / 6) * 2) * 20 + (q0 % 6) * 2) * 256 + scol;
    int rb1 = ((b1 * 20 + (q1 / 6) * 2) * 20 + (q1 % 6) * 2) * 256 + scol;
    const int ksbase = ks * NCH32;

    int wid = tid >> 6, lane = tid & 63;
    int wr = wid >> 1, wc = wid & 1;            // wave tile 32(M) x 64(N)
    int fr = lane & 15, sl = lane >> 4;         // sl: logical 8-elem k-slot (0..3)

    int offAh[2], offAl[2], offB2[4];
    #pragma unroll
    for (int i = 0; i < 2; ++i) {
        int ra = wr * 32 + i * 16 + fr;
        int x = ra & 7;
        offAh[i] = ra * 64 + ((sl ^ x) << 3);
        offAl[i] = ra * 64 + (((sl | 4) ^ x) << 3);
    }
    #pragma unroll
    for (int jj = 0; jj < 4; ++jj) {
        int rb = wc * 64 + jj * 16 + fr;        // 0..127
        int slog = sl | ((rb >> 6) << 2);
        offB2[jj] = (rb & 63) * 64 + ((slog ^ (rb & 7)) << 3);
    }

#define STAGE(pp, c) do {                                                       \
        int g_ = ksbase + (c);                                                  \
        int kw_ = g_ >> 3;                                                      \
        int koff_ = ((kw_ / 9) * 20 + (kw_ % 9)) * 256 + (g_ & 7) * 32;         \
        int aoff_ = (c) * 32;                                                   \
        async16(&sA[pp][tid * 8],         pA0 + aoff_);                         \
        async16(&sA[pp][(tid + 256) * 8], pA1 + aoff_);                         \
        async16(&sB[pp][tid * 8],         spk + rb0 + koff_);                   \
        async16(&sB[pp][(tid + 256) * 8], spk + rb1 + koff_);                   \
    } while (0)

    f32x4 acc[2][4] = {};
    STAGE(0, 0);
    for (int c = 0; c < NCH32; ++c) {
        int pp = c & 1;
        __syncthreads();                 // drains chunk c's loads; frees buf pp^1
        if (c + 1 < NCH32) STAGE(pp ^ 1, c + 1);   // overlaps with compute below
        bf16x8 ah[2], al[2], bv[4];
        #pragma unroll
        for (int i = 0; i < 2; ++i) {
            ah[i] = *(const bf16x8*)&sA[pp][offAh[i]];
            al[i] = *(const bf16x8*)&sA[pp][offAl[i]];
        }
        #pragma unroll
        for (int jj = 0; jj < 4; ++jj)
            bv[jj] = *(const bf16x8*)&sB[pp][offB2[jj]];
        #pragma unroll
        for (int i = 0; i < 2; ++i)
            #pragma unroll
            for (int jj = 0; jj < 4; ++jj) {
                acc[i][jj] = __builtin_amdgcn_mfma_f32_16x16x32_bf16(ah[i], bv[jj], acc[i][jj], 0, 0, 0);
                acc[i][jj] = __builtin_amdgcn_mfma_f32_16x16x32_bf16(al[i], bv[jj], acc[i][jj], 0, 0, 0);
            }
    }
#undef STAGE
    int colb = lane & 15, rb4 = (lane >> 4) * 4;
    float* Co = Cp + (size_t)ks * (MM * NN);
    #pragma unroll
    for (int i = 0; i < 2; ++i)
        #pragma unroll
        for (int jj = 0; jj < 4; ++jj) {
            int gm = tm * 64 + wr * 32 + i * 16 + rb4;
            int gn = tn * 128 + wc * 64 + jj * 16 + colb;
            #pragma unroll
            for (int q = 0; q < 4; ++q)
                Co[(size_t)(gm + q) * NN + gn] = acc[i][jj][q];
        }
}

// ---------------- dig: fused split-K reduce + prim membrane + u_hat + dig membrane ----------------
__global__ __launch_bounds__(320) void k_dig(const float* __restrict__ Cp,
                                             const float* __restrict__ pb,
                                             float* __restrict__ pmem,
                                             const float* __restrict__ W,
                                             const float* __restrict__ bias,
                                             const float* __restrict__ bij,
                                             float* __restrict__ dmem,
                                             uint8_t* __restrict__ age,
                                             float* __restrict__ sjp) {
    __shared__ float ps[256];   // [r(4)][bl(8)][i(8)]
    int r0 = blockIdx.x * 4;
    int by = blockIdx.y;
    int tid = threadIdx.x;
    for (int l = tid; l < 256; l += 320) {
        int r = l >> 6, bl = (l >> 3) & 7, i = l & 7;
        int f = (r0 + r) * 8 + i;
        int oc = f / 36, pos = f % 36;
        int b = by * 8 + bl;
        int n = b * 36 + pos;
        float sacc = pb[oc];
        #pragma unroll
        for (int kss = 0; kss < KSPLIT; ++kss)
            sacc += Cp[(size_t)kss * (MM * NN) + oc * NN + n];
        size_t pidx = (size_t)b * 9216 + f;
        float m = pmem[pidx];
        float pso = (m > THRESH) ? THRESH : 0.f;
        m = (m - pso) * DECAY + sacc;
        pmem[pidx] = m;
        ps[l] = (m > THRESH) ? 1.f : 0.f;
    }
    __syncthreads();
    int co = tid % 160, bh = tid / 160;
    int c = co >> 4, o = co & 15;
    float bo = bias[o];
    float sacc[4] = {0.f, 0.f, 0.f, 0.f};
    for (int r = 0; r < 4; ++r) {
        int rr = r0 + r;
        const float* wp = W + ((size_t)((rr * 10 + c) * 16 + o)) * 8;
        f32x4 w0 = *(const f32x4*)wp;
        f32x4 w1 = *(const f32x4*)(wp + 4);
        float bv = bij[rr * 10 + c];
        #pragma unroll
        for (int bb = 0; bb < 4; ++bb) {
            int bl = bh * 4 + bb;
            const float* p8 = &ps[(r * 8 + bl) * 8];
            f32x4 pa = *(const f32x4*)p8;
            f32x4 pc = *(const f32x4*)(p8 + 4);
            float u = bo + w0.x * pa.x + w0.y * pa.y + w0.z * pa.z + w0.w * pa.w
                         + w1.x * pc.x + w1.y * pc.y + w1.z * pc.z + w1.w * pc.w;
            size_t idx = ((size_t)((by * 8 + bl) * 1152 + rr)) * 160 + co;
            float m = dmem[idx];
            float psv = (m > THRESH) ? THRESH : 0.f;
            m = (m - psv) * DECAY + u;
            dmem[idx] = m;
            bool sp = m > THRESH;
            if (sp) sacc[bb] += bv;
            uint8_t a = age[idx];                    // 0 = never spiked
            age[idx] = sp ? (uint8_t)1 : (a ? (uint8_t)(a + 1) : (uint8_t)0);
        }
    }
    size_t pbase = ((size_t)(by * 288 + blockIdx.x)) * 1280;
    #pragma unroll
    for (int bb = 0; bb < 4; ++bb)
        sjp[pbase + (bh * 4 + bb) * 160 + co] = sacc[bb];
}

// ---------------- k_mix: blocks 0-39 = dig2 reduce+membrane+out; blocks 40+ = convmem(t+1) ----------------
__global__ void k_mix(const float* __restrict__ sjp, float* __restrict__ d2mem,
                      float* __restrict__ omem, float* __restrict__ cmem,
                      const float* __restrict__ cout, unsigned short* __restrict__ spk) {
    int bx = blockIdx.x;
    int tid = threadIdx.x;
    if (bx < 20) {
        int e = bx * 256 + tid;     // 0..5119
        int y = e / 1280, rem = e % 1280;
        float s = 0.f;
        for (int x = 0; x < 288; ++x)
            s += sjp[((size_t)(y * 288 + x)) * 1280 + rem];
        float m = d2mem[e];
        float ps = (m > THRESH) ? THRESH : 0.f;
        d2mem[e] = (m - ps) * DECAY + s;
        omem[e] += s;
    } else {
        int i = (bx - 20) * 256 + tid;
        if (i < CONV_ELEMS / 4) convmem_body(i, cmem, cout, spk);
    }
}

// ---------------- b_ij update (age: 0=never, else steps-since-spike+1) ----------------
__global__ void k_bij(const uint8_t* __restrict__ age, const float* __restrict__ d2mem,
                      float* __restrict__ bij) {
    int g = blockIdx.x * 256 + threadIdx.x;
    if (g >= RR * 160) return;
    int r = g / 160, co = g % 160, c = co / 16, o = co & 15;
    const float dtr = expf(-1.0f / 1.5f);
    float tab[5];
    tab[0] = 1.f;
    #pragma unroll
    for (int k = 1; k < 5; ++k) tab[k] = tab[k - 1] * dtr;
    float acc = 0.f;
    for (int b = 0; b < B_; ++b) {
        uint8_t a = age[(size_t)b * (RR * 160) + g];
        float tv = (a == 0 || a > 5) ? 0.f : tab[a - 1];
        float d2 = (d2mem[b * 160 + co] > THRESH) ? 1.f : 0.f;
        acc += (tv - 0.1f) * d2;
    }
    #pragma unroll
    for (int off = 1; off < 16; off <<= 1) acc += __shfl_xor(acc, off);
    if (o == 0) {
        float bo = bij[r * 10 + c];
        bo = fminf(fmaxf(bo, -0.05f), 1.0f);
        bij[r * 10 + c] = bo + 0.0008f * (acc * (1.0f / 32.0f));
    }
}

// ---------------- final: classes ----------------
__global__ void k_out(const float* __restrict__ omem, float* __restrict__ out) {
    int i = blockIdx.x * 64 + threadIdx.x;
    if (i >= B_ * CC) return;
    int b = i / 10, c = i % 10;
    float s = 0.f;
    #pragma unroll
    for (int o = 0; o < 16; ++o) {
        float v = omem[b * 160 + c * 16 + o] / 5.0f;
        s += v * v;
    }
    out[i] = sqrtf(s);
}

extern "C" void kernel_launch(void* const* d_in, const int* in_sizes, int n_in,
                              void* d_out, int out_size, void* d_ws, size_t ws_size,
                              hipStream_t stream) {
    const float* data   = (const float*)d_in[0];
    const float* conv_w = (const float*)d_in[1];
    const float* conv_b = (const float*)d_in[2];
    const float* prim_w = (const float*)d_in[3];
    const float* prim_b = (const float*)d_in[4];
    const float* W      = (const float*)d_in[5];
    const float* bias   = (const float*)d_in[6];
    float* out = (float*)d_out;

    char* ws = (char*)d_ws;
    size_t off = 0;
    auto alloc = [&](size_t bytes) {
        void* p = ws + off;
        off = (off + bytes + 255) & ~(size_t)255;
        return p;
    };
    // --- contiguous zero-init state block ---
    size_t zbase = off;
    float*          conv_mem = (float*)alloc((size_t)CONV_ELEMS * 4);
    float*          prim_mem = (float*)alloc((size_t)PRIM_ELEMS * 4);
    float*          dig_mem  = (float*)alloc((size_t)DIG_ELEMS * 4);
    float*          dig2_mem = (float*)alloc(5120 * 4);
    float*          out_mem  = (float*)alloc(5120 * 4);
    uint8_t*        age      = (uint8_t*)alloc(DIG_ELEMS);
    size_t zbytes = off - zbase;
    // --- non-state scratch ---
    float*          conv_out = (float*)alloc((size_t)CONV_ELEMS * 4);
    unsigned short* conv_spk = (unsigned short*)alloc((size_t)CONV_ELEMS * 2);
    float*          sjp      = (float*)alloc((size_t)1152 * 1280 * 4);
    float*          bij      = (float*)alloc(RR * CC * 4);
    unsigned short* Ahi      = (unsigned short*)alloc((size_t)MM * KK * 2);
    unsigned short* Alo      = (unsigned short*)alloc((size_t)MM * KK * 2);
    float*          Cp       = (float*)alloc((size_t)KSPLIT * MM * NN * 4);

    hipMemsetAsync(ws + zbase, 0, zbytes, stream);

    k_init_bij<<<(RR * CC + 255) / 256, 256, 0, stream>>>(bij);
    k_conv1<<<dim3(32, 16), 320, 0, stream>>>(data, conv_w, conv_b, conv_out);
    k_wsplit<<<MM, 256, 0, stream>>>(prim_w, Ahi, Alo);
    k_convmem<<<(CONV_ELEMS / 4 + 255) / 256, 256, 0, stream>>>(conv_mem, conv_out, conv_spk);

    for (int t = 0; t < TSTEPS; ++t) {
        k_gemm<<<864, 256, 0, stream>>>(Ahi, Alo, conv_spk, Cp);
        k_dig<<<dim3(288, 4), 320, 0, stream>>>(Cp, prim_b, prim_mem, W, bias, bij, dig_mem, age, sjp);
        int mixg = (t < TSTEPS - 1) ? (20 + (CONV_ELEMS / 4 + 255) / 256) : 20;
        k_mix<<<mixg, 256, 0, stream>>>(sjp, dig2_mem, out_mem, conv_mem, conv_out, conv_spk);
        k_bij<<<(RR * 160 + 255) / 256, 256, 0, stream>>>(age, dig2_mem, bij);
    }
    k_out<<<(B_ * CC + 63) / 64, 64, 0, stream>>>(out_mem, out);
}

// Round 7
// 424.085 us; speedup vs baseline: 1.1996x; 1.1996x over previous
//
#include <hip/hip_runtime.h>
#include <stdint.h>

#define THRESH 0.5f
#define DECAY  0.2f
#define TSTEPS 5

#define B_        32
#define CONV_ELEMS (32*256*20*20)   // 3,276,800  (NHWC: [b][y][x][ic])
#define RR        1152
#define CC        10
#define PRIM_ELEMS (32*1152*8)      // 294,912
#define DIG_ELEMS  (32*1152*160)    // 5,898,240
#define MM        256
#define NN        1152
#define KK        20736             // 81 windows * 256 ic, k' = kw*256+ic
#define KSPLIT    18
#define NCH32     36                // 32-elem K chunks per ks slice (36*32 = 1152)

typedef __attribute__((ext_vector_type(8))) short bf16x8;
typedef __attribute__((ext_vector_type(4))) float f32x4;
typedef __attribute__((ext_vector_type(4))) unsigned short u16x4;

__device__ __forceinline__ unsigned short f32_to_bf16(float f) {
    uint32_t u = __float_as_uint(f);
    uint32_t r = 0x7FFFu + ((u >> 16) & 1u);
    return (unsigned short)((u + r) >> 16);
}
__device__ __forceinline__ float bf16_to_f32(unsigned short h) {
    return __uint_as_float(((uint32_t)h) << 16);
}

__device__ __forceinline__ void async16(void* l, const void* g) {
    __builtin_amdgcn_global_load_lds(
        (const __attribute__((address_space(1))) uint32_t*)g,
        (__attribute__((address_space(3))) uint32_t*)l, 16, 0, 0);
}

// ---------------- init ----------------
__global__ void k_init_bij(float* bij) {
    int i = blockIdx.x * 256 + threadIdx.x;
    if (i < RR * CC) bij[i] = 1.0f / 1152.0f;
}

// ---------------- conv1 (once): compute NCHW-style, emit NHWC via LDS transpose ----------------
__global__ __launch_bounds__(320) void k_conv1(const float* __restrict__ data,
                                               const float* __restrict__ cw,
                                               const float* __restrict__ cb,
                                               float* __restrict__ out) {
    __shared__ float sdat[784];
    __shared__ float swt[1296];
    __shared__ float sout[20 * 333];
    int b = blockIdx.x, og = blockIdx.y;
    int tid = threadIdx.x;
    for (int i = tid; i < 196; i += 320)
        ((f32x4*)sdat)[i] = ((const f32x4*)(data + b * 784))[i];
    for (int i = tid; i < 324; i += 320)
        ((f32x4*)swt)[i] = ((const f32x4*)(cw + og * 1296))[i];
    __syncthreads();
    int ocl = tid / 20, y = tid % 20;
    float acc[20];
    #pragma unroll
    for (int x = 0; x < 20; ++x) acc[x] = 0.f;
    const float* wb = &swt[ocl * 81];
    #pragma unroll
    for (int ky = 0; ky < 9; ++ky) {
        const float* dr = &sdat[(y + ky) * 28];
        float d[28];
        #pragma unroll
        for (int t4 = 0; t4 < 7; ++t4) {
            f32x4 v = ((const f32x4*)dr)[t4];
            d[t4 * 4 + 0] = v.x; d[t4 * 4 + 1] = v.y;
            d[t4 * 4 + 2] = v.z; d[t4 * 4 + 3] = v.w;
        }
        float w[9];
        #pragma unroll
        for (int q = 0; q < 9; ++q) w[q] = wb[ky * 9 + q];
        #pragma unroll
        for (int kx = 0; kx < 9; ++kx)
            #pragma unroll
            for (int x = 0; x < 20; ++x)
                acc[x] += d[x + kx] * w[kx];
    }
    float bias = cb[og * 16 + ocl];
    #pragma unroll
    for (int x = 0; x < 20; ++x)
        sout[y * 333 + x * 16 + ocl] = fmaxf(acc[x] + bias, 0.f);
    __syncthreads();
    const size_t base = (size_t)b * 102400 + og * 16;
    for (int f = tid; f < 6400; f += 320) {
        int yy = f / 320, rem = f % 320;
        out[base + (size_t)(f >> 4) * 256 + (f & 15)] = sout[yy * 333 + rem];
    }
}

// ---------------- weight split+relayout (once): A'[oc][kw*256+ic] bf16 hi/lo ----------------
__global__ __launch_bounds__(256) void k_wsplit(const float* __restrict__ w,
                                                unsigned short* __restrict__ hi,
                                                unsigned short* __restrict__ lo) {
    int oc = blockIdx.x, ic = threadIdx.x;
    const float* src = w + (size_t)oc * 20736 + ic * 81;
    unsigned short* dh = hi + (size_t)oc * 20736 + ic;
    unsigned short* dl = lo + (size_t)oc * 20736 + ic;
    for (int kw = 0; kw < 81; ++kw) {
        float f = src[kw];
        unsigned short h = f32_to_bf16(f);
        dh[kw * 256] = h;
        dl[kw * 256] = f32_to_bf16(f - bf16_to_f32(h));
    }
}

// ---------------- conv membrane update body ----------------
__device__ __forceinline__ void convmem_body(int i, float* mem, const float* cout,
                                             unsigned short* spk) {
    f32x4 m = ((f32x4*)mem)[i];
    f32x4 c = ((const f32x4*)cout)[i];
    u16x4 sp;
    #pragma unroll
    for (int j = 0; j < 4; ++j) {
        float mv = m[j];
        float ps = (mv > THRESH) ? THRESH : 0.f;
        mv = (mv - ps) * DECAY + c[j];
        m[j] = mv;
        sp[j] = (mv > THRESH) ? (unsigned short)0x3F80 : (unsigned short)0;
    }
    ((f32x4*)mem)[i] = m;
    ((u16x4*)spk)[i] = sp;
}

__global__ void k_convmem(float* __restrict__ mem, const float* __restrict__ cout,
                          unsigned short* __restrict__ spk) {
    int i = blockIdx.x * 256 + threadIdx.x;
    if (i >= CONV_ELEMS / 4) return;
    convmem_body(i, mem, cout, spk);
}

// ---------------- fused-B split-K MFMA GEMM, 64x128 tile, BK=32, paired-row LDS ----------------
// 3-buffer pipeline, prefetch distance 2, counted vmcnt(4) + raw s_barrier (T3/T4):
// every wave waits for its OWN chunk-c DMA loads before the barrier, so after the
// barrier chunk c is fully in LDS while chunk c+1's loads stay in flight.
__global__ __launch_bounds__(256) void k_gemm(const unsigned short* __restrict__ Ahi,
                                              const unsigned short* __restrict__ Alo,
                                              const unsigned short* __restrict__ spk,
                                              float* __restrict__ Cp) {
    __shared__ unsigned short sA[3][64 * 64];
    __shared__ unsigned short sB[3][64 * 64];
    int bid = blockIdx.x;
    int slot = bid & 7, j = bid >> 3;          // 648 = 8 * 81
    int tm = slot & 3, kpar = slot >> 2;       // blocks sharing (tm,kpar) share bid%8 -> same XCD
    int tn = j / 9, ks2 = j % 9;
    int ks = ks2 * 2 + kpar;                   // 0..17
    int tid = threadIdx.x;

    // staging geometry: LDS row r0 = tid>>3 (pass0) / +32 (pass1); phys slot p = tid&7
    int r0 = tid >> 3;
    int p8 = tid & 7;
    int s = p8 ^ (r0 & 7);                     // logical slot (same for both passes)
    int scol = (s & 3) * 8;                    // k-col offset within 32-elem chunk
    // A source (hi for s<4, lo for s>=4)
    size_t arow = (size_t)(tm * 64 + r0) * KK + (size_t)ks * 1152 + scol;
    const unsigned short* pA0 = (s < 4 ? Ahi : Alo) + arow;
    const unsigned short* pA1 = pA0 + (size_t)32 * KK;
    // B source rows
    int nr0 = tn * 128 + ((s < 4) ? r0 : r0 + 64);
    int nr1 = tn * 128 + ((s < 4) ? r0 + 32 : r0 + 96);
    int b0 = nr0 / 36, q0 = nr0 % 36, b1 = nr1 / 36, q1 = nr1 % 36;
    int rb0 = ((b0 * 20 + (q0 / 6) * 2) * 20 + (q0 % 6) * 2) * 256 + scol;
    int rb1 = ((b1 * 20 + (q1 / 6) * 2) * 20 + (q1 % 6) * 2) * 256 + scol;
    const int ksbase = ks * NCH32;

    int wid = tid >> 6, lane = tid & 63;
    int wr = wid >> 1, wc = wid & 1;            // wave tile 32(M) x 64(N)
    int fr = lane & 15, sl = lane >> 4;         // sl: logical 8-elem k-slot (0..3)

    int offAh[2], offAl[2], offB2[4];
    #pragma unroll
    for (int i = 0; i < 2; ++i) {
        int ra = wr * 32 + i * 16 + fr;
        int x = ra & 7;
        offAh[i] = ra * 64 + ((sl ^ x) << 3);
        offAl[i] = ra * 64 + (((sl | 4) ^ x) << 3);
    }
    #pragma unroll
    for (int jj = 0; jj < 4; ++jj) {
        int rb = wc * 64 + jj * 16 + fr;        // 0..127
        int slog = sl | ((rb >> 6) << 2);
        offB2[jj] = (rb & 63) * 64 + ((slog ^ (rb & 7)) << 3);
    }

#define STAGE(pp, c) do {                                                       \
        int g_ = ksbase + (c);                                                  \
        int kw_ = g_ >> 3;                                                      \
        int koff_ = ((kw_ / 9) * 20 + (kw_ % 9)) * 256 + (g_ & 7) * 32;         \
        int aoff_ = (c) * 32;                                                   \
        async16(&sA[pp][tid * 8],         pA0 + aoff_);                         \
        async16(&sA[pp][(tid + 256) * 8], pA1 + aoff_);                         \
        async16(&sB[pp][tid * 8],         spk + rb0 + koff_);                   \
        async16(&sB[pp][(tid + 256) * 8], spk + rb1 + koff_);                   \
    } while (0)

    f32x4 acc[2][4] = {};
    STAGE(0, 0);
    STAGE(1, 1);
    for (int c = 0; c < NCH32; ++c) {
        // wait for chunk c's 4 DMA loads (leave chunk c+1's 4 in flight); T4: never
        // drain to 0 except on the final chunk.
        if (c + 1 < NCH32) { asm volatile("s_waitcnt vmcnt(4)" ::: "memory"); }
        else               { asm volatile("s_waitcnt vmcnt(0)" ::: "memory"); }
        __builtin_amdgcn_s_barrier();
        // buffer (c+2)%3 held chunk c-1, whose reads finished before this barrier
        if (c + 2 < NCH32) STAGE((c + 2) % 3, c + 2);
        int pp = c % 3;
        bf16x8 ah[2], al[2], bv[4];
        #pragma unroll
        for (int i = 0; i < 2; ++i) {
            ah[i] = *(const bf16x8*)&sA[pp][offAh[i]];
            al[i] = *(const bf16x8*)&sA[pp][offAl[i]];
        }
        #pragma unroll
        for (int jj = 0; jj < 4; ++jj)
            bv[jj] = *(const bf16x8*)&sB[pp][offB2[jj]];
        #pragma unroll
        for (int i = 0; i < 2; ++i)
            #pragma unroll
            for (int jj = 0; jj < 4; ++jj) {
                acc[i][jj] = __builtin_amdgcn_mfma_f32_16x16x32_bf16(ah[i], bv[jj], acc[i][jj], 0, 0, 0);
                acc[i][jj] = __builtin_amdgcn_mfma_f32_16x16x32_bf16(al[i], bv[jj], acc[i][jj], 0, 0, 0);
            }
    }
#undef STAGE
    int colb = lane & 15, rb4 = (lane >> 4) * 4;
    float* Co = Cp + (size_t)ks * (MM * NN);
    #pragma unroll
    for (int i = 0; i < 2; ++i)
        #pragma unroll
        for (int jj = 0; jj < 4; ++jj) {
            int gm = tm * 64 + wr * 32 + i * 16 + rb4;
            int gn = tn * 128 + wc * 64 + jj * 16 + colb;
            #pragma unroll
            for (int q = 0; q < 4; ++q)
                Co[(size_t)(gm + q) * NN + gn] = acc[i][jj][q];
        }
}

// ---------------- dig: fused split-K reduce + prim membrane + u_hat + dig membrane ----------------
__global__ __launch_bounds__(320) void k_dig(const float* __restrict__ Cp,
                                             const float* __restrict__ pb,
                                             float* __restrict__ pmem,
                                             const float* __restrict__ W,
                                             const float* __restrict__ bias,
                                             const float* __restrict__ bij,
                                             float* __restrict__ dmem,
                                             uint8_t* __restrict__ age,
                                             float* __restrict__ sjp) {
    __shared__ float ps[256];   // [r(4)][bl(8)][i(8)]
    int r0 = blockIdx.x * 4;
    int by = blockIdx.y;
    int tid = threadIdx.x;
    for (int l = tid; l < 256; l += 320) {
        int r = l >> 6, bl = (l >> 3) & 7, i = l & 7;
        int f = (r0 + r) * 8 + i;
        int oc = f / 36, pos = f % 36;
        int b = by * 8 + bl;
        int n = b * 36 + pos;
        float sacc = pb[oc];
        #pragma unroll
        for (int kss = 0; kss < KSPLIT; ++kss)
            sacc += Cp[(size_t)kss * (MM * NN) + oc * NN + n];
        size_t pidx = (size_t)b * 9216 + f;
        float m = pmem[pidx];
        float pso = (m > THRESH) ? THRESH : 0.f;
        m = (m - pso) * DECAY + sacc;
        pmem[pidx] = m;
        ps[l] = (m > THRESH) ? 1.f : 0.f;
    }
    __syncthreads();
    int co = tid % 160, bh = tid / 160;
    int c = co >> 4, o = co & 15;
    float bo = bias[o];
    float sacc[4] = {0.f, 0.f, 0.f, 0.f};
    for (int r = 0; r < 4; ++r) {
        int rr = r0 + r;
        const float* wp = W + ((size_t)((rr * 10 + c) * 16 + o)) * 8;
        f32x4 w0 = *(const f32x4*)wp;
        f32x4 w1 = *(const f32x4*)(wp + 4);
        float bv = bij[rr * 10 + c];
        #pragma unroll
        for (int bb = 0; bb < 4; ++bb) {
            int bl = bh * 4 + bb;
            const float* p8 = &ps[(r * 8 + bl) * 8];
            f32x4 pa = *(const f32x4*)p8;
            f32x4 pc = *(const f32x4*)(p8 + 4);
            float u = bo + w0.x * pa.x + w0.y * pa.y + w0.z * pa.z + w0.w * pa.w
                         + w1.x * pc.x + w1.y * pc.y + w1.z * pc.z + w1.w * pc.w;
            size_t idx = ((size_t)((by * 8 + bl) * 1152 + rr)) * 160 + co;
            float m = dmem[idx];
            float psv = (m > THRESH) ? THRESH : 0.f;
            m = (m - psv) * DECAY + u;
            dmem[idx] = m;
            bool sp = m > THRESH;
            if (sp) sacc[bb] += bv;
            uint8_t a = age[idx];                    // 0 = never spiked
            age[idx] = sp ? (uint8_t)1 : (a ? (uint8_t)(a + 1) : (uint8_t)0);
        }
    }
    size_t pbase = ((size_t)(by * 288 + blockIdx.x)) * 1280;
    #pragma unroll
    for (int bb = 0; bb < 4; ++bb)
        sjp[pbase + (bh * 4 + bb) * 160 + co] = sacc[bb];
}

// ---------------- dig2a: reduce sjp partials (k-sliced, no atomics, deterministic) ----------------
__global__ void k_dig2a(const float* __restrict__ sjp, float* __restrict__ sjp2) {
    int e = blockIdx.x * 256 + threadIdx.x;   // 0..5119
    int y = e / 1280, rem = e % 1280;
    int x0 = blockIdx.y * 24;
    float a = 0.f;
    #pragma unroll 8
    for (int x = x0; x < x0 + 24; ++x)
        a += sjp[((size_t)(y * 288 + x)) * 1280 + rem];
    sjp2[blockIdx.y * 5120 + e] = a;
}

// ---------------- k_mix: blocks 0-19 = dig2b (final reduce + membrane + out); rest = convmem(t+1) ----------------
__global__ void k_mix(const float* __restrict__ sjp2, float* __restrict__ d2mem,
                      float* __restrict__ omem, float* __restrict__ cmem,
                      const float* __restrict__ cout, unsigned short* __restrict__ spk) {
    int bx = blockIdx.x;
    int tid = threadIdx.x;
    if (bx < 20) {
        int e = bx * 256 + tid;     // 0..5119
        float s = 0.f;
        #pragma unroll
        for (int k = 0; k < 12; ++k) s += sjp2[k * 5120 + e];
        float m = d2mem[e];
        float ps = (m > THRESH) ? THRESH : 0.f;
        d2mem[e] = (m - ps) * DECAY + s;
        omem[e] += s;
    } else {
        int i = (bx - 20) * 256 + tid;
        if (i < CONV_ELEMS / 4) convmem_body(i, cmem, cout, spk);
    }
}

// ---------------- b_ij update (age: 0=never, else steps-since-spike+1) ----------------
__global__ void k_bij(const uint8_t* __restrict__ age, const float* __restrict__ d2mem,
                      float* __restrict__ bij) {
    int g = blockIdx.x * 256 + threadIdx.x;
    if (g >= RR * 160) return;
    int r = g / 160, co = g % 160, c = co / 16, o = co & 15;
    const float dtr = expf(-1.0f / 1.5f);
    float tab[5];
    tab[0] = 1.f;
    #pragma unroll
    for (int k = 1; k < 5; ++k) tab[k] = tab[k - 1] * dtr;
    float acc = 0.f;
    for (int b = 0; b < B_; ++b) {
        uint8_t a = age[(size_t)b * (RR * 160) + g];
        float tv = (a == 0 || a > 5) ? 0.f : tab[a - 1];
        float d2 = (d2mem[b * 160 + co] > THRESH) ? 1.f : 0.f;
        acc += (tv - 0.1f) * d2;
    }
    #pragma unroll
    for (int off = 1; off < 16; off <<= 1) acc += __shfl_xor(acc, off);
    if (o == 0) {
        float bo = bij[r * 10 + c];
        bo = fminf(fmaxf(bo, -0.05f), 1.0f);
        bij[r * 10 + c] = bo + 0.0008f * (acc * (1.0f / 32.0f));
    }
}

// ---------------- final: classes ----------------
__global__ void k_out(const float* __restrict__ omem, float* __restrict__ out) {
    int i = blockIdx.x * 64 + threadIdx.x;
    if (i >= B_ * CC) return;
    int b = i / 10, c = i % 10;
    float s = 0.f;
    #pragma unroll
    for (int o = 0; o < 16; ++o) {
        float v = omem[b * 160 + c * 16 + o] / 5.0f;
        s += v * v;
    }
    out[i] = sqrtf(s);
}

extern "C" void kernel_launch(void* const* d_in, const int* in_sizes, int n_in,
                              void* d_out, int out_size, void* d_ws, size_t ws_size,
                              hipStream_t stream) {
    const float* data   = (const float*)d_in[0];
    const float* conv_w = (const float*)d_in[1];
    const float* conv_b = (const float*)d_in[2];
    const float* prim_w = (const float*)d_in[3];
    const float* prim_b = (const float*)d_in[4];
    const float* W      = (const float*)d_in[5];
    const float* bias   = (const float*)d_in[6];
    float* out = (float*)d_out;

    char* ws = (char*)d_ws;
    size_t off = 0;
    auto alloc = [&](size_t bytes) {
        void* p = ws + off;
        off = (off + bytes + 255) & ~(size_t)255;
        return p;
    };
    // --- contiguous zero-init state block ---
    size_t zbase = off;
    float*          conv_mem = (float*)alloc((size_t)CONV_ELEMS * 4);
    float*          prim_mem = (float*)alloc((size_t)PRIM_ELEMS * 4);
    float*          dig_mem  = (float*)alloc((size_t)DIG_ELEMS * 4);
    float*          dig2_mem = (float*)alloc(5120 * 4);
    float*          out_mem  = (float*)alloc(5120 * 4);
    uint8_t*        age      = (uint8_t*)alloc(DIG_ELEMS);
    size_t zbytes = off - zbase;
    // --- non-state scratch ---
    float*          conv_out = (float*)alloc((size_t)CONV_ELEMS * 4);
    unsigned short* conv_spk = (unsigned short*)alloc((size_t)CONV_ELEMS * 2);
    float*          sjp      = (float*)alloc((size_t)1152 * 1280 * 4);
    float*          sjp2     = (float*)alloc((size_t)12 * 5120 * 4);
    float*          bij      = (float*)alloc(RR * CC * 4);
    unsigned short* Ahi      = (unsigned short*)alloc((size_t)MM * KK * 2);
    unsigned short* Alo      = (unsigned short*)alloc((size_t)MM * KK * 2);
    float*          Cp       = (float*)alloc((size_t)KSPLIT * MM * NN * 4);

    hipMemsetAsync(ws + zbase, 0, zbytes, stream);

    k_init_bij<<<(RR * CC + 255) / 256, 256, 0, stream>>>(bij);
    k_conv1<<<dim3(32, 16), 320, 0, stream>>>(data, conv_w, conv_b, conv_out);
    k_wsplit<<<MM, 256, 0, stream>>>(prim_w, Ahi, Alo);
    k_convmem<<<(CONV_ELEMS / 4 + 255) / 256, 256, 0, stream>>>(conv_mem, conv_out, conv_spk);

    for (int t = 0; t < TSTEPS; ++t) {
        k_gemm<<<648, 256, 0, stream>>>(Ahi, Alo, conv_spk, Cp);
        k_dig<<<dim3(288, 4), 320, 0, stream>>>(Cp, prim_b, prim_mem, W, bias, bij, dig_mem, age, sjp);
        k_dig2a<<<dim3(20, 12), 256, 0, stream>>>(sjp, sjp2);
        int mixg = (t < TSTEPS - 1) ? (20 + (CONV_ELEMS / 4 + 255) / 256) : 20;
        k_mix<<<mixg, 256, 0, stream>>>(sjp2, dig2_mem, out_mem, conv_mem, conv_out, conv_spk);
        k_bij<<<(RR * 160 + 255) / 256, 256, 0, stream>>>(age, dig2_mem, bij);
    }
    k_out<<<(B_ * CC + 63) / 64, 64, 0, stream>>>(out_mem, out);
}